// Round 17
// baseline (125.042 us; speedup 1.0000x reference)
//
#include <hip/hip_runtime.h>
#include <hip/hip_bf16.h>
#include <math.h>

#define B_ 4
#define T_ 512
#define D_ 768
#define H_ 12
#define FF_ 3072
#define DK_ 64
#define NTOK (B_*T_)
#define NEGV -1e9f

typedef unsigned short u16;
typedef __bf16 bfx8 __attribute__((ext_vector_type(8)));
typedef float f32x4 __attribute__((ext_vector_type(4)));
typedef u16 u16x8 __attribute__((ext_vector_type(8)));
typedef u16 u16x4 __attribute__((ext_vector_type(4)));

__device__ __forceinline__ u16 f2bf(float f) {
  union { float f; unsigned u; } v; v.f = f;
  unsigned r = (v.u + 0x7FFFu + ((v.u >> 16) & 1u)) >> 16;   // RNE
  return (u16)r;
}

__device__ __forceinline__ float bf2f(u16 u) {
  union { unsigned u; float f; } c; c.u = (unsigned)u << 16; return c.f;
}

__device__ __forceinline__ void glds16(const u16* g, u16* l) {
  __builtin_amdgcn_global_load_lds((const __attribute__((address_space(1))) void*)g,
                                   (__attribute__((address_space(3))) void*)l, 16, 0, 0);
}

// exact-GELU via Abramowitz-Stegun 7.1.26 erf (|err| < 1.5e-7)
__device__ __forceinline__ float gelu_f(float x) {
  float ax = fabsf(x) * 0.7071067811865475f;
  float t = 1.0f / fmaf(0.3275911f, ax, 1.0f);
  float poly = t * fmaf(t, fmaf(t, fmaf(t, fmaf(t, 1.061405429f, -1.453152027f),
                                        1.421413741f), -0.284496736f), 0.254829592f);
  float erfv = 1.0f - poly * __expf(-ax * ax);
  erfv = x >= 0.f ? erfv : -erfv;
  return 0.5f * x * (1.0f + erfv);
}

// ---------------- fused prep: weight transposes + LN1 + temporal-bias MLP
__global__ __launch_bounds__(256) void prep_kernel(
    const float* __restrict__ x,
    const float* __restrict__ wq, const float* __restrict__ wk,
    const float* __restrict__ wv, const float* __restrict__ wp,
    const float* __restrict__ fc1, const float* __restrict__ fc2,
    u16* wqT, u16* wkT, u16* wvT, u16* wpT, u16* fc1T, u16* fc2T,
    const float* __restrict__ ln1g, const float* __restrict__ ln1b, u16* __restrict__ hbuf,
    const float* __restrict__ tmat, const int* __restrict__ pad,
    const float* __restrict__ tb1w, const float* __restrict__ tb1b,
    const float* __restrict__ tb2w, const float* __restrict__ tb2b,
    u16* __restrict__ biasM)
{
  const int bid = blockIdx.x;
  const int tid = threadIdx.x;
  if (bid < 6912) {
    // ---- weight transpose+cast  (K,N) f32 -> (N,K) bf16
    __shared__ float tile[32][33];
    const float* in; u16* outp; int K, N, local;
    if (bid < 2304) {
      int m = bid / 576; local = bid % 576; K = 768; N = 768;
      in   = m == 0 ? wq  : (m == 1 ? wk  : (m == 2 ? wv  : wp));
      outp = m == 0 ? wqT : (m == 1 ? wkT : (m == 2 ? wvT : wpT));
    } else if (bid < 4608) {
      local = bid - 2304; K = 768; N = 3072; in = fc1; outp = fc1T;
    } else {
      local = bid - 4608; K = 3072; N = 768; in = fc2; outp = fc2T;
    }
    const int nt = N / 32;
    const int n0 = (local % nt) * 32, k0 = (local / nt) * 32;
    const int tx = tid & 31, ty = tid >> 5;   // (32,8)
    #pragma unroll
    for (int i = 0; i < 4; ++i) {
      int r = ty + i * 8;
      tile[r][tx] = in[(size_t)(k0 + r) * N + n0 + tx];
    }
    __syncthreads();
    // vectorized write: one u16x4 (8B) per thread
    const int nloc = tid >> 3;          // 0..31
    const int k4   = (tid & 7) * 4;     // 0..28
    u16x4 vv;
    #pragma unroll
    for (int jj = 0; jj < 4; ++jj) vv[jj] = f2bf(tile[k4 + jj][nloc]);
    *(u16x4*)&outp[(size_t)(n0 + nloc) * K + k0 + k4] = vv;
  } else if (bid < 8960) {
    // ---- LN1
    const int row = bid - 6912;
    const float* xr = x + (size_t)row * D_;
    float v0 = xr[tid], v1 = xr[tid + 256], v2 = xr[tid + 512];
    float s = v0 + v1 + v2;
    float sq = v0 * v0 + v1 * v1 + v2 * v2;
    #pragma unroll
    for (int o = 32; o > 0; o >>= 1) { s += __shfl_down(s, o); sq += __shfl_down(sq, o); }
    __shared__ float ss[4], s2[4];
    int w = tid >> 6;
    if ((tid & 63) == 0) { ss[w] = s; s2[w] = sq; }
    __syncthreads();
    s = ss[0] + ss[1] + ss[2] + ss[3];
    sq = s2[0] + s2[1] + s2[2] + s2[3];
    float mean = s * (1.0f / 768.0f);
    float inv = rsqrtf(sq * (1.0f / 768.0f) - mean * mean + 1e-5f);
    u16* orow = hbuf + (size_t)row * D_;
    orow[tid]       = f2bf((v0 - mean) * inv * ln1g[tid]       + ln1b[tid]);
    orow[tid + 256] = f2bf((v1 - mean) * inv * ln1g[tid + 256] + ln1b[tid + 256]);
    orow[tid + 512] = f2bf((v2 - mean) * inv * ln1g[tid + 512] + ln1b[tid + 512]);
  } else {
    // ---- temporal bias MLP -> bf16 (causal-skip: masked (i,j) never consumed)
    const int lidx = bid - 8960;
    const int i_row = (lidx >> 1) & 511;
    const int j0 = (lidx & 1) * 256;
    if (i_row != 0 && j0 > i_row) return;    // block-uniform, before any barrier
    __shared__ float sw1[64], sb1[64], sw2[64];
    if (tid < 64) {
      sw1[tid] = tb1w[tid];
      sb1[tid] = tb1b[tid];
      sw2[tid] = tb2w[tid];
    }
    __syncthreads();
    size_t idx = (size_t)lidx * 256 + tid;
    float tm = 1.0f / __logf(2.718281828459045f + tmat[idx]);
    float acc = tb2b[0];
    #pragma unroll
    for (int t = 0; t < 64; ++t) {
      float u = fmaf(tm, sw1[t], sb1[t]);
      u = u > 0.0f ? u : 0.2f * u;          // leaky_relu(0.2)
      acc = fmaf(u, sw2[t], acc);
    }
    biasM[idx] = f2bf((pad[idx] == 0) ? NEGV : acc);
  }
}

// ---------------- 8-wave 128x128 mainloop, TWO K-tiles per barrier (4 LDS bufs)
// Fragment-order LDS (conflict-free). Prologue stages tiles 0,1; each iter:
// vmcnt(0) -> barrier -> issue tiles 2it+2,2it+3 into the buffer pair freed by
// the PREVIOUS barrier (race-free) -> 12 ds_read + 16 MFMA. Halves barriers.
__device__ __forceinline__ void gemm_tile_w8x2(
    const u16* __restrict__ A, const u16* __restrict__ BT,
    int K, int nk, int m0, int n0, int k0,
    u16* As, u16* Bs, f32x4 acc[2][4])
{
  const int tid = threadIdx.x;
  const int w = tid >> 6, lane = tid & 63;
  const int lr = lane & 15, hi = lane >> 4;
  const int sr = lane >> 2;                  // row within 16-row group
  const int so = (lane & 3) * 8;             // k offset
  const u16* gA = A  + (size_t)(m0 + w * 16 + sr) * K + k0 + so;
  const u16* gB = BT + (size_t)(n0 + w * 16 + sr) * K + k0 + so;
  u16* la = As + w * 512;                    // wave-uniform LDS base (1KB group)
  u16* lb = Bs + w * 512;
  const int ga = (w >> 1) * 2;               // A group base
  const int gb = (w & 1) * 4;                // B group base
  const int fo = (lr * 4 + hi) * 8;          // fragment slot offset
  const int nkp = nk >> 1;
#define ISSUE_T(kk, b) do { \
    glds16(gA + (size_t)(kk) * 32, la + (b) * 4096); \
    glds16(gB + (size_t)(kk) * 32, lb + (b) * 4096); } while (0)
  ISSUE_T(0, 0);
  ISSUE_T(1, 1);
  int cb = 0;
  for (int it = 0; it < nkp; ++it) {
    asm volatile("s_waitcnt vmcnt(0)" ::: "memory");
    __builtin_amdgcn_sched_barrier(0);
    __builtin_amdgcn_s_barrier();
    __builtin_amdgcn_sched_barrier(0);
    if (it + 1 < nkp) {                 // refill freed pair; covered by this iter's MFMAs
      ISSUE_T(2 * it + 2, cb ^ 2);
      ISSUE_T(2 * it + 3, (cb ^ 2) + 1);
    }
    #pragma unroll
    for (int t2 = 0; t2 < 2; ++t2) {
      const u16* Asc = As + (cb + t2) * 4096;
      const u16* Bsc = Bs + (cb + t2) * 4096;
      bfx8 af[2], bfr[4];
      #pragma unroll
      for (int t = 0; t < 2; ++t)
        af[t] = *(const bfx8*)&Asc[(ga + t) * 512 + fo];
      #pragma unroll
      for (int t = 0; t < 4; ++t)
        bfr[t] = *(const bfx8*)&Bsc[(gb + t) * 512 + fo];
      #pragma unroll
      for (int rt = 0; rt < 2; ++rt)
        #pragma unroll
        for (int ct = 0; ct < 4; ++ct)
          acc[rt][ct] = __builtin_amdgcn_mfma_f32_16x16x32_bf16(af[rt], bfr[ct], acc[rt][ct], 0, 0, 0);
    }
    cb ^= 2;
  }
#undef ISSUE_T
}

// QKV fused, 1-D grid (288), XCD-aware: each XCD owns 2 M-panels
__global__ __launch_bounds__(512) void gemm_qkv(
    const u16* __restrict__ A,
    const u16* __restrict__ wqT, const u16* __restrict__ wkT, const u16* __restrict__ wvT,
    const float* __restrict__ bq, const float* __restrict__ bk, const float* __restrict__ bv,
    u16* __restrict__ qo, u16* __restrict__ ko, u16* __restrict__ vo)
{
  __shared__ u16 As[4 * 128 * 32];
  __shared__ u16 Bs[4 * 128 * 32];
  const int bid = blockIdx.x;
  const int xcd = bid & 7, idx = bid >> 3;     // 36 per XCD
  const int y = xcd * 2 + (idx & 1);           // M-panel 0..15
  const int r2 = idx >> 1;                     // 0..17
  const int xt = r2 % 6, z = r2 / 6;           // n-tile, matrix id
  const u16* BT = z == 0 ? wqT : (z == 1 ? wkT : wvT);
  const float* bias = z == 0 ? bq : (z == 1 ? bk : bv);
  u16* outp = z == 0 ? qo : (z == 1 ? ko : vo);
  const float scale = z == 0 ? 0.125f : 1.0f;   // DK^-0.5 folded into q
  const int m0 = y * 128, n0 = xt * 128;
  f32x4 acc[2][4];
  #pragma unroll
  for (int a = 0; a < 2; ++a)
    #pragma unroll
    for (int bb = 0; bb < 4; ++bb) acc[a][bb] = (f32x4){0.f, 0.f, 0.f, 0.f};
  gemm_tile_w8x2(A, BT, D_, D_ / 32, m0, n0, 0, As, Bs, acc);
  const int tid = threadIdx.x;
  const int w = tid >> 6, lane = tid & 63;
  const int lr = lane & 15, hi = lane >> 4;
  const int wm = (w >> 1) * 32, wn = (w & 1) * 64;
  #pragma unroll
  for (int rt = 0; rt < 2; ++rt)
    #pragma unroll
    for (int ct = 0; ct < 4; ++ct)
      #pragma unroll
      for (int r = 0; r < 4; ++r) {
        int m = m0 + wm + rt * 16 + hi * 4 + r;
        int n = n0 + wn + ct * 16 + lr;
        float val = (acc[rt][ct][r] + bias[n]) * scale;
        int b = m >> 9, t = m & 511, hh = n >> 6, d = n & 63;
        if (z < 2) outp[(((size_t)b * H_ + hh) * T_ + t) * DK_ + d] = f2bf(val);
        else       outp[(((size_t)b * H_ + hh) * DK_ + d) * T_ + t] = f2bf(val);
      }
}

// split-K GEMM -> bf16 partials part[kz][M][N]; 1-D grid, XCD-aware (nx n-tiles)
__global__ __launch_bounds__(512) void gemm_part_bf16(
    const u16* __restrict__ A, const u16* __restrict__ BT,
    u16* __restrict__ part, int M, int N, int K, int Ksplit, int nx)
{
  __shared__ u16 As[4 * 128 * 32];
  __shared__ u16 Bs[4 * 128 * 32];
  const int bid = blockIdx.x;
  const int xcd = bid & 7, idx = bid >> 3;
  const int y = xcd * 2 + (idx & 1);           // M-panel 0..15
  const int r2 = idx >> 1;
  const int xt = r2 % nx, kz = r2 / nx;
  const int m0 = y * 128, n0 = xt * 128;
  f32x4 acc[2][4];
  #pragma unroll
  for (int a = 0; a < 2; ++a)
    #pragma unroll
    for (int bb = 0; bb < 4; ++bb) acc[a][bb] = (f32x4){0.f, 0.f, 0.f, 0.f};
  gemm_tile_w8x2(A, BT, K, Ksplit / 32, m0, n0, kz * Ksplit, As, Bs, acc);
  const int tid = threadIdx.x;
  const int w = tid >> 6, lane = tid & 63;
  const int lr = lane & 15, hi = lane >> 4;
  const int wm = (w >> 1) * 32, wn = (w & 1) * 64;
  u16* pp = part + (size_t)kz * M * N;
  #pragma unroll
  for (int rt = 0; rt < 2; ++rt)
    #pragma unroll
    for (int ct = 0; ct < 4; ++ct)
      #pragma unroll
      for (int r = 0; r < 4; ++r) {
        int m = m0 + wm + rt * 16 + hi * 4 + r;
        int n = n0 + wn + ct * 16 + lr;
        pp[(size_t)m * N + n] = f2bf(acc[rt][ct][r]);
      }
}

// proj reduce (4 bf16 partials) + x + bp, fused LN2 -> x1 (f32) + h2 (bf16)
// 192 threads/row; thread t owns 4 contiguous cols
__global__ __launch_bounds__(192) void reduce_ln(
    const u16* __restrict__ part, const float* __restrict__ x, const float* __restrict__ bp,
    const float* __restrict__ g, const float* __restrict__ bta,
    float* __restrict__ x1, u16* __restrict__ h2)
{
  const int row = blockIdx.x;
  const int tid = threadIdx.x;              // 0..191
  const int c0 = tid * 4;
  const size_t base = (size_t)row * D_ + c0;
  const size_t slab = (size_t)NTOK * D_;
  float4 xv = *(const float4*)&x[base];
  float4 bv = *(const float4*)&bp[c0];
  float v[4] = {xv.x + bv.x, xv.y + bv.y, xv.z + bv.z, xv.w + bv.w};
  #pragma unroll
  for (int kz = 0; kz < 4; ++kz) {
    u16x4 pv = *(const u16x4*)&part[kz * slab + base];
    #pragma unroll
    for (int j = 0; j < 4; ++j) v[j] += bf2f(pv[j]);
  }
  float s = v[0] + v[1] + v[2] + v[3];
  float sq = v[0] * v[0] + v[1] * v[1] + v[2] * v[2] + v[3] * v[3];
  #pragma unroll
  for (int o = 32; o > 0; o >>= 1) { s += __shfl_down(s, o); sq += __shfl_down(sq, o); }
  __shared__ float ss[3], s2[3];
  int w = tid >> 6;
  if ((tid & 63) == 0) { ss[w] = s; s2[w] = sq; }
  __syncthreads();
  s = ss[0] + ss[1] + ss[2];
  sq = s2[0] + s2[1] + s2[2];
  float mean = s * (1.0f / 768.0f);
  float inv = rsqrtf(sq * (1.0f / 768.0f) - mean * mean + 1e-5f);
  float4 gv = *(const float4*)&g[c0];
  float4 tv = *(const float4*)&bta[c0];
  float4 xo = {v[0], v[1], v[2], v[3]};
  *(float4*)&x1[base] = xo;
  u16x4 ho;
  ho[0] = f2bf((v[0] - mean) * inv * gv.x + tv.x);
  ho[1] = f2bf((v[1] - mean) * inv * gv.y + tv.y);
  ho[2] = f2bf((v[2] - mean) * inv * gv.z + tv.z);
  ho[3] = f2bf((v[3] - mean) * inv * gv.w + tv.w);
  *(u16x4*)&h2[base] = ho;
}

// FFN2 stage 2: out = sum of 4 bf16 partials + fc2b + x1 (8 elems/thread)
__global__ __launch_bounds__(256) void reduce_out(
    const u16* __restrict__ part, const float* __restrict__ x1,
    const float* __restrict__ bias, float* __restrict__ out)
{
  const size_t base = ((size_t)blockIdx.x * 256 + threadIdx.x) * 8;
  const size_t slab = (size_t)NTOK * D_;
  const int nb = (int)(base % D_);
  float s[8];
  float4 a0 = *(const float4*)&x1[base];
  float4 a1 = *(const float4*)&x1[base + 4];
  float4 b0 = *(const float4*)&bias[nb];
  float4 b1 = *(const float4*)&bias[nb + 4];
  s[0] = a0.x + b0.x; s[1] = a0.y + b0.y; s[2] = a0.z + b0.z; s[3] = a0.w + b0.w;
  s[4] = a1.x + b1.x; s[5] = a1.y + b1.y; s[6] = a1.z + b1.z; s[7] = a1.w + b1.w;
  #pragma unroll
  for (int kz = 0; kz < 4; ++kz) {
    u16x8 pv = *(const u16x8*)&part[kz * slab + base];
    #pragma unroll
    for (int j = 0; j < 8; ++j) s[j] += bf2f(pv[j]);
  }
  float4 o0 = {s[0], s[1], s[2], s[3]};
  float4 o1 = {s[4], s[5], s[6], s[7]};
  *(float4*)&out[base]     = o0;
  *(float4*)&out[base + 4] = o1;
}

// FFN1: gelu epilogue -> bf16; 1-D grid (384), XCD-aware (24 n-tiles)
__global__ __launch_bounds__(512) void gemm_gelu(
    const u16* __restrict__ A, const u16* __restrict__ BT,
    const float* __restrict__ bias, u16* __restrict__ outp, int M, int N, int K)
{
  __shared__ u16 As[4 * 128 * 32];
  __shared__ u16 Bs[4 * 128 * 32];
  const int bid = blockIdx.x;
  const int xcd = bid & 7, idx = bid >> 3;     // 48 per XCD
  const int y = xcd * 2 + (idx & 1);           // M-panel 0..15
  const int xt = idx >> 1;                     // n-tile 0..23
  const int m0 = y * 128, n0 = xt * 128;
  f32x4 acc[2][4];
  #pragma unroll
  for (int a = 0; a < 2; ++a)
    #pragma unroll
    for (int bb = 0; bb < 4; ++bb) acc[a][bb] = (f32x4){0.f, 0.f, 0.f, 0.f};
  gemm_tile_w8x2(A, BT, K, K / 32, m0, n0, 0, As, Bs, acc);
  const int tid = threadIdx.x;
  const int w = tid >> 6, lane = tid & 63;
  const int lr = lane & 15, hi = lane >> 4;
  const int wm = (w >> 1) * 32, wn = (w & 1) * 64;
  #pragma unroll
  for (int rt = 0; rt < 2; ++rt)
    #pragma unroll
    for (int ct = 0; ct < 4; ++ct)
      #pragma unroll
      for (int r = 0; r < 4; ++r) {
        int m = m0 + wm + rt * 16 + hi * 4 + r;
        int n = n0 + wn + ct * 16 + lr;
        float val = acc[rt][ct][r] + bias[n];
        outp[(size_t)m * N + n] = f2bf(gelu_f(val));
      }
}

// ---------------- attention v4: 32 q-rows per block, causal column skipping,
// scores in registers, P bf16 swizzled LDS, V-frags shared across row-groups.
__global__ __launch_bounds__(256) void attn_kernel(
    const u16* __restrict__ q, const u16* __restrict__ k, const u16* __restrict__ vT,
    const u16* __restrict__ biasM, u16* __restrict__ ao)
{
  __shared__ u16 P[32 * 512];            // unnormalized bf16 P, XOR-swizzled (32 KB)
  __shared__ float pmax[128], psum[128]; // [wave][row 0..31]
  const int tid = threadIdx.x;
  const int w = tid >> 6, lane = tid & 63;
  const int lr = lane & 15, hi = lane >> 4, lk = hi * 8;

  const int bid = blockIdx.x;
  const int xcd = bid & 7, idx = bid >> 3;     // 96 blocks per XCD
  const int bh = xcd * 6 + (idx >> 4);         // 6 bh per XCD
  const int i0 = (idx & 15) * 32;
  const int b = bh / H_, h = bh % H_;
  const int tmax = (i0 == 0) ? 31 : ((i0 >> 4) + 1);   // 16-col tiles
  const int nks  = (i0 == 0) ? 16 : ((i0 >> 5) + 1);   // 32-col PV k-tiles

  bfx8 qf[2][2];
  #pragma unroll
  for (int g = 0; g < 2; ++g)
    #pragma unroll
    for (int ks = 0; ks < 2; ++ks)
      qf[g][ks] = *(const bfx8*)(q + ((size_t)bh * T_ + i0 + g * 16 + lr) * DK_ + ks * 32 + lk);
  f32x4 acc[8][2];
  float mx[2][4];
  #pragma unroll
  for (int g = 0; g < 2; ++g)
    #pragma unroll
    for (int r = 0; r < 4; ++r) mx[g][r] = -3.4e38f;
  #pragma unroll
  for (int ct = 0; ct < 8; ++ct) {
    const int t = ct * 4 + w;
    if (t > tmax) continue;              // wave-uniform skip
    const int j0 = t * 16;
    bfx8 kf0 = *(const bfx8*)(k + ((size_t)bh * T_ + j0 + lr) * DK_ + lk);
    bfx8 kf1 = *(const bfx8*)(k + ((size_t)bh * T_ + j0 + lr) * DK_ + 32 + lk);
    const int j = j0 + lr;
    __builtin_amdgcn_s_setprio(1);
    #pragma unroll
    for (int g = 0; g < 2; ++g) {
      f32x4 a0 = (f32x4){0.f, 0.f, 0.f, 0.f};
      a0 = __builtin_amdgcn_mfma_f32_16x16x32_bf16(qf[g][0], kf0, a0, 0, 0, 0);
      a0 = __builtin_amdgcn_mfma_f32_16x16x32_bf16(qf[g][1], kf1, a0, 0, 0, 0);
      acc[ct][g] = a0;
    }
    __builtin_amdgcn_s_setprio(0);
    #pragma unroll
    for (int g = 0; g < 2; ++g)
      #pragma unroll
      for (int r = 0; r < 4; ++r) {
        int i = i0 + g * 16 + hi * 4 + r;
        float s = acc[ct][g][r] + bf2f(biasM[((size_t)b * T_ + i) * T_ + j]);
        if (j > i && i != 0) s = NEGV;   // causal; CLS row 0 fully visible
        acc[ct][g][r] = s;
        mx[g][r] = fmaxf(mx[g][r], s);
      }
  }
  #pragma unroll
  for (int o = 1; o < 16; o <<= 1)
    #pragma unroll
    for (int g = 0; g < 2; ++g)
      #pragma unroll
      for (int r = 0; r < 4; ++r) mx[g][r] = fmaxf(mx[g][r], __shfl_xor(mx[g][r], o));
  if (lr == 0) {
    #pragma unroll
    for (int g = 0; g < 2; ++g)
      #pragma unroll
      for (int r = 0; r < 4; ++r) pmax[w * 32 + g * 16 + hi * 4 + r] = mx[g][r];
  }
  __syncthreads();

  float M2[2][4], sm[2][4];
  #pragma unroll
  for (int g = 0; g < 2; ++g)
    #pragma unroll
    for (int r = 0; r < 4; ++r) {
      int row = g * 16 + hi * 4 + r;
      M2[g][r] = fmaxf(fmaxf(pmax[row], pmax[32 + row]), fmaxf(pmax[64 + row], pmax[96 + row]));
      sm[g][r] = 0.f;
    }
  char* Pb = (char*)P;
  #pragma unroll
  for (int ct = 0; ct < 8; ++ct) {
    const int t = ct * 4 + w;
    if (t > tmax) continue;
    const int col = t * 16 + lr;
    #pragma unroll
    for (int g = 0; g < 2; ++g)
      #pragma unroll
      for (int r = 0; r < 4; ++r) {
        float pexp = __expf(acc[ct][g][r] - M2[g][r]);
        sm[g][r] += pexp;
        int row = g * 16 + hi * 4 + r;
        int byte = (row * 1024 + col * 2) ^ ((row & 7) << 4);
        *(u16*)(Pb + byte) = f2bf(pexp);
      }
  }
  #pragma unroll
  for (int o = 1; o < 16; o <<= 1)
    #pragma unroll
    for (int g = 0; g < 2; ++g)
      #pragma unroll
      for (int r = 0; r < 4; ++r) sm[g][r] += __shfl_xor(sm[g][r], o);
  if (lr == 0) {
    #pragma unroll
    for (int g = 0; g < 2; ++g)
      #pragma unroll
      for (int r = 0; r < 4; ++r) psum[w * 32 + g * 16 + hi * 4 + r] = sm[g][r];
  }
  __syncthreads();

  float rinv[2][4];
  #pragma unroll
  for (int g = 0; g < 2; ++g)
    #pragma unroll
    for (int r = 0; r < 4; ++r) {
      int row = g * 16 + hi * 4 + r;
      rinv[g][r] = 1.0f / (psum[row] + psum[32 + row] + psum[64 + row] + psum[96 + row]);
    }

  {
    const int n0 = w * 16;
    f32x4 oa0 = (f32x4){0.f, 0.f, 0.f, 0.f};
    f32x4 oa1 = (f32x4){0.f, 0.f, 0.f, 0.f};
    for (int ks = 0; ks < nks; ++ks) {
      bfx8 vf = *(const bfx8*)(vT + ((size_t)bh * DK_ + n0 + lr) * T_ + ks * 32 + lk);
      int byte0 = (lr * 1024 + (ks * 32 + lk) * 2) ^ ((lr & 7) << 4);
      int byte1 = ((16 + lr) * 1024 + (ks * 32 + lk) * 2) ^ ((lr & 7) << 4);
      bfx8 pa0 = *(const bfx8*)(Pb + byte0);
      bfx8 pa1 = *(const bfx8*)(Pb + byte1);
      __builtin_amdgcn_s_setprio(1);
      oa0 = __builtin_amdgcn_mfma_f32_16x16x32_bf16(pa0, vf, oa0, 0, 0, 0);
      oa1 = __builtin_amdgcn_mfma_f32_16x16x32_bf16(pa1, vf, oa1, 0, 0, 0);
      __builtin_amdgcn_s_setprio(0);
    }
    #pragma unroll
    for (int r = 0; r < 4; ++r) {
      int i = i0 + hi * 4 + r;
      ao[((size_t)b * T_ + i) * D_ + h * DK_ + n0 + lr] = f2bf(oa0[r] * rinv[0][r]);
    }
    #pragma unroll
    for (int r = 0; r < 4; ++r) {
      int i = i0 + 16 + hi * 4 + r;
      ao[((size_t)b * T_ + i) * D_ + h * DK_ + n0 + lr] = f2bf(oa1[r] * rinv[1][r]);
    }
  }
}

extern "C" void kernel_launch(void* const* d_in, const int* in_sizes, int n_in,
                              void* d_out, int out_size, void* d_ws, size_t ws_size,
                              hipStream_t stream) {
  (void)in_sizes; (void)n_in; (void)out_size; (void)ws_size;
  const float* x    = (const float*)d_in[0];
  const float* tmat = (const float*)d_in[1];
  const int*   pad  = (const int*)d_in[2];
  const float* wq = (const float*)d_in[3];  const float* bq = (const float*)d_in[4];
  const float* wk = (const float*)d_in[5];  const float* bk = (const float*)d_in[6];
  const float* wv = (const float*)d_in[7];  const float* bv = (const float*)d_in[8];
  const float* wp = (const float*)d_in[9];  const float* bp = (const float*)d_in[10];
  const float* tb1w = (const float*)d_in[11]; const float* tb1b = (const float*)d_in[12];
  const float* tb2w = (const float*)d_in[13]; const float* tb2b = (const float*)d_in[14];
  const float* fc1w = (const float*)d_in[15]; const float* fc1b = (const float*)d_in[16];
  const float* fc2w = (const float*)d_in[17]; const float* fc2b = (const float*)d_in[18];
  const float* ln1g = (const float*)d_in[19]; const float* ln1b = (const float*)d_in[20];
  const float* ln2g = (const float*)d_in[21]; const float* ln2b = (const float*)d_in[22];
  float* out = (float*)d_out;

  // ---- workspace layout
  char* p = (char*)d_ws;
  u16* wqT  = (u16*)p; p += (size_t)768 * 768 * 2;
  u16* wkT  = (u16*)p; p += (size_t)768 * 768 * 2;
  u16* wvT  = (u16*)p; p += (size_t)768 * 768 * 2;
  u16* wpT  = (u16*)p; p += (size_t)768 * 768 * 2;
  u16* fc1T = (u16*)p; p += (size_t)768 * 3072 * 2;
  u16* fc2T = (u16*)p; p += (size_t)3072 * 768 * 2;
  float* x1 = (float*)p; p += (size_t)NTOK * D_ * 4;
  u16* gbuf = (u16*)p; p += (size_t)NTOK * FF_ * 2;
  u16* hbuf = (u16*)p; p += (size_t)NTOK * D_ * 2;
  u16* qb   = (u16*)p; p += (size_t)NTOK * D_ * 2;
  u16* kb   = (u16*)p; p += (size_t)NTOK * D_ * 2;
  u16* vTb  = (u16*)p; p += (size_t)NTOK * D_ * 2;
  u16* biasM = (u16*)p; p += (size_t)B_ * T_ * T_ * 2;
  u16* ao   = (u16*)p; p += (size_t)NTOK * D_ * 2;
  u16* h2   = (u16*)p; p += (size_t)NTOK * D_ * 2;
  u16* partF = (u16*)p; p += (size_t)4 * NTOK * D_ * 2;   // bf16 partials (4 slabs)

  // prep: transposes + LN1 + bias MLP in one dispatch
  prep_kernel<<<13056, 256, 0, stream>>>(x, wq, wk, wv, wp, fc1w, fc2w,
                                         wqT, wkT, wvT, wpT, fc1T, fc2T,
                                         ln1g, ln1b, hbuf,
                                         tmat, pad, tb1w, tb1b, tb2w, tb2b, biasM);

  gemm_qkv<<<288, 512, 0, stream>>>(hbuf, wqT, wkT, wvT, bq, bk, bv, qb, kb, vTb);
  attn_kernel<<<768, 256, 0, stream>>>(qb, kb, vTb, biasM, ao);

  // proj: split-K=4 bf16 partials (384 blocks), then reduce fused with LN2
  gemm_part_bf16<<<384, 512, 0, stream>>>(ao, wpT, partF, NTOK, 768, 768, 192, 6);
  reduce_ln<<<NTOK, 192, 0, stream>>>(partF, x, bp, ln2g, ln2b, x1, h2);

  // FFN1 (384 blocks)
  gemm_gelu<<<384, 512, 0, stream>>>(h2, fc1T, fc1b, gbuf, NTOK, FF_, 768);

  // FFN2: split-K=4 (384 blocks) -> bf16 partials, then vectorized reduce
  gemm_part_bf16<<<384, 512, 0, stream>>>(gbuf, fc2T, partF, NTOK, 768, 3072, 768, 6);
  reduce_out<<<NTOK * D_ / 8 / 256, 256, 0, stream>>>(partF, x1, fc2b, out);
}

// Round 18
// 123.980 us; speedup vs baseline: 1.0086x; 1.0086x over previous
//
#include <hip/hip_runtime.h>
#include <hip/hip_bf16.h>
#include <math.h>

#define B_ 4
#define T_ 512
#define D_ 768
#define H_ 12
#define FF_ 3072
#define DK_ 64
#define NTOK (B_*T_)
#define NEGV -1e9f

typedef unsigned short u16;
typedef __bf16 bfx8 __attribute__((ext_vector_type(8)));
typedef float f32x4 __attribute__((ext_vector_type(4)));
typedef u16 u16x8 __attribute__((ext_vector_type(8)));
typedef u16 u16x4 __attribute__((ext_vector_type(4)));

__device__ __forceinline__ u16 f2bf(float f) {
  union { float f; unsigned u; } v; v.f = f;
  unsigned r = (v.u + 0x7FFFu + ((v.u >> 16) & 1u)) >> 16;   // RNE
  return (u16)r;
}

__device__ __forceinline__ float bf2f(u16 u) {
  union { unsigned u; float f; } c; c.u = (unsigned)u << 16; return c.f;
}

__device__ __forceinline__ void glds16(const u16* g, u16* l) {
  __builtin_amdgcn_global_load_lds((const __attribute__((address_space(1))) void*)g,
                                   (__attribute__((address_space(3))) void*)l, 16, 0, 0);
}

// exact-GELU via Abramowitz-Stegun 7.1.26 erf (|err| < 1.5e-7)
__device__ __forceinline__ float gelu_f(float x) {
  float ax = fabsf(x) * 0.7071067811865475f;
  float t = 1.0f / fmaf(0.3275911f, ax, 1.0f);
  float poly = t * fmaf(t, fmaf(t, fmaf(t, fmaf(t, 1.061405429f, -1.453152027f),
                                        1.421413741f), -0.284496736f), 0.254829592f);
  float erfv = 1.0f - poly * __expf(-ax * ax);
  erfv = x >= 0.f ? erfv : -erfv;
  return 0.5f * x * (1.0f + erfv);
}

// ---------------- fused prep: weight transposes + LN1 + temporal-bias MLP
__global__ __launch_bounds__(256) void prep_kernel(
    const float* __restrict__ x,
    const float* __restrict__ wq, const float* __restrict__ wk,
    const float* __restrict__ wv, const float* __restrict__ wp,
    const float* __restrict__ fc1, const float* __restrict__ fc2,
    u16* wqT, u16* wkT, u16* wvT, u16* wpT, u16* fc1T, u16* fc2T,
    const float* __restrict__ ln1g, const float* __restrict__ ln1b, u16* __restrict__ hbuf,
    const float* __restrict__ tmat, const int* __restrict__ pad,
    const float* __restrict__ tb1w, const float* __restrict__ tb1b,
    const float* __restrict__ tb2w, const float* __restrict__ tb2b,
    u16* __restrict__ biasM)
{
  const int bid = blockIdx.x;
  const int tid = threadIdx.x;
  if (bid < 6912) {
    // ---- weight transpose+cast  (K,N) f32 -> (N,K) bf16
    __shared__ float tile[32][33];
    const float* in; u16* outp; int K, N, local;
    if (bid < 2304) {
      int m = bid / 576; local = bid % 576; K = 768; N = 768;
      in   = m == 0 ? wq  : (m == 1 ? wk  : (m == 2 ? wv  : wp));
      outp = m == 0 ? wqT : (m == 1 ? wkT : (m == 2 ? wvT : wpT));
    } else if (bid < 4608) {
      local = bid - 2304; K = 768; N = 3072; in = fc1; outp = fc1T;
    } else {
      local = bid - 4608; K = 3072; N = 768; in = fc2; outp = fc2T;
    }
    const int nt = N / 32;
    const int n0 = (local % nt) * 32, k0 = (local / nt) * 32;
    const int tx = tid & 31, ty = tid >> 5;   // (32,8)
    #pragma unroll
    for (int i = 0; i < 4; ++i) {
      int r = ty + i * 8;
      tile[r][tx] = in[(size_t)(k0 + r) * N + n0 + tx];
    }
    __syncthreads();
    // vectorized write: one u16x4 (8B) per thread
    const int nloc = tid >> 3;          // 0..31
    const int k4   = (tid & 7) * 4;     // 0..28
    u16x4 vv;
    #pragma unroll
    for (int jj = 0; jj < 4; ++jj) vv[jj] = f2bf(tile[k4 + jj][nloc]);
    *(u16x4*)&outp[(size_t)(n0 + nloc) * K + k0 + k4] = vv;
  } else if (bid < 8960) {
    // ---- LN1
    const int row = bid - 6912;
    const float* xr = x + (size_t)row * D_;
    float v0 = xr[tid], v1 = xr[tid + 256], v2 = xr[tid + 512];
    float s = v0 + v1 + v2;
    float sq = v0 * v0 + v1 * v1 + v2 * v2;
    #pragma unroll
    for (int o = 32; o > 0; o >>= 1) { s += __shfl_down(s, o); sq += __shfl_down(sq, o); }
    __shared__ float ss[4], s2[4];
    int w = tid >> 6;
    if ((tid & 63) == 0) { ss[w] = s; s2[w] = sq; }
    __syncthreads();
    s = ss[0] + ss[1] + ss[2] + ss[3];
    sq = s2[0] + s2[1] + s2[2] + s2[3];
    float mean = s * (1.0f / 768.0f);
    float inv = rsqrtf(sq * (1.0f / 768.0f) - mean * mean + 1e-5f);
    u16* orow = hbuf + (size_t)row * D_;
    orow[tid]       = f2bf((v0 - mean) * inv * ln1g[tid]       + ln1b[tid]);
    orow[tid + 256] = f2bf((v1 - mean) * inv * ln1g[tid + 256] + ln1b[tid + 256]);
    orow[tid + 512] = f2bf((v2 - mean) * inv * ln1g[tid + 512] + ln1b[tid + 512]);
  } else {
    // ---- temporal bias MLP -> bf16 (causal-skip: masked (i,j) never consumed)
    const int lidx = bid - 8960;
    const int i_row = (lidx >> 1) & 511;
    const int j0 = (lidx & 1) * 256;
    if (i_row != 0 && j0 > i_row) return;    // block-uniform, before any barrier
    __shared__ float sw1[64], sb1[64], sw2[64];
    if (tid < 64) {
      sw1[tid] = tb1w[tid];
      sb1[tid] = tb1b[tid];
      sw2[tid] = tb2w[tid];
    }
    __syncthreads();
    size_t idx = (size_t)lidx * 256 + tid;
    float tm = 1.0f / __logf(2.718281828459045f + tmat[idx]);
    float acc = tb2b[0];
    #pragma unroll
    for (int t = 0; t < 64; ++t) {
      float u = fmaf(tm, sw1[t], sb1[t]);
      u = u > 0.0f ? u : 0.2f * u;          // leaky_relu(0.2)
      acc = fmaf(u, sw2[t], acc);
    }
    biasM[idx] = f2bf((pad[idx] == 0) ? NEGV : acc);
  }
}

// ---------------- 8-wave (512-thread) depth-2 pipelined GEMM mainloop, 128x128 tile
// LDS in MFMA-FRAGMENT ORDER: the tile is 8 groups of 16 rows; group g (1KB) holds
// slot s = r*4+kg at offset s*16B with data A[g*16+r][kg*8..+8]. Wave w stages
// group g=w (lane L -> row w*16+(L>>2), cols (L&3)*8..+8; linear LDS dest).
// Fragment read: lane l reads slot (l&15)*4+(l>>4) -> distinct 16B slots, zero
// bank conflicts.
__device__ __forceinline__ void gemm_tile_w8(
    const u16* __restrict__ A, const u16* __restrict__ BT,
    int K, int nk, int m0, int n0, int k0,
    u16* As, u16* Bs, f32x4 acc[2][4])
{
  const int tid = threadIdx.x;
  const int w = tid >> 6, lane = tid & 63;
  const int lr = lane & 15, hi = lane >> 4;
  const int sr = lane >> 2;                  // subtile row within group (0..15)
  const int so = (lane & 3) * 8;             // k offset
  const u16* gA = A  + (size_t)(m0 + w * 16 + sr) * K + k0 + so;
  const u16* gB = BT + (size_t)(n0 + w * 16 + sr) * K + k0 + so;
  u16* la = As + w * 512;                    // wave-uniform LDS base (1KB group)
  u16* lb = Bs + w * 512;
  const int ga = (w >> 1) * 2;               // A group base (wave rows wm=ga*16)
  const int gb = (w & 1) * 4;                // B group base (wave cols wn=gb*16)
  const int fo = (lr * 4 + hi) * 8;          // fragment slot offset (u16 elems)
#define ISSUE_TILE(kk, b) do { \
    glds16(gA + (size_t)(kk) * 32, la + (b) * 4096); \
    glds16(gB + (size_t)(kk) * 32, lb + (b) * 4096); } while (0)
  ISSUE_TILE(0, 0);
  if (nk > 1) ISSUE_TILE(1, 1);
  int cb = 0;
  for (int kt = 0; kt < nk; ++kt) {
    if (kt < nk - 2) asm volatile("s_waitcnt vmcnt(2)" ::: "memory");
    else             asm volatile("s_waitcnt vmcnt(0)" ::: "memory");
    __builtin_amdgcn_sched_barrier(0);
    __builtin_amdgcn_s_barrier();
    __builtin_amdgcn_sched_barrier(0);
    const u16* Asc = As + cb * 4096;
    const u16* Bsc = Bs + cb * 4096;
    bfx8 af[2], bfr[4];
    #pragma unroll
    for (int t = 0; t < 2; ++t)
      af[t] = *(const bfx8*)&Asc[(ga + t) * 512 + fo];
    #pragma unroll
    for (int t = 0; t < 4; ++t)
      bfr[t] = *(const bfx8*)&Bsc[(gb + t) * 512 + fo];
    if (kt + 2 < nk) {                 // issue BEFORE compute: MFMA covers latency
      int nb = cb + 2; if (nb >= 3) nb -= 3;
      ISSUE_TILE(kt + 2, nb);
    }
    #pragma unroll
    for (int rt = 0; rt < 2; ++rt)
      #pragma unroll
      for (int ct = 0; ct < 4; ++ct)
        acc[rt][ct] = __builtin_amdgcn_mfma_f32_16x16x32_bf16(af[rt], bfr[ct], acc[rt][ct], 0, 0, 0);
    cb = cb + 1; if (cb >= 3) cb = 0;
  }
#undef ISSUE_TILE
}

// QKV fused, 1-D grid (288), XCD-aware: each XCD owns 2 M-panels
__global__ __launch_bounds__(512) void gemm_qkv(
    const u16* __restrict__ A,
    const u16* __restrict__ wqT, const u16* __restrict__ wkT, const u16* __restrict__ wvT,
    const float* __restrict__ bq, const float* __restrict__ bk, const float* __restrict__ bv,
    u16* __restrict__ qo, u16* __restrict__ ko, u16* __restrict__ vo)
{
  __shared__ u16 As[3 * 128 * 32];
  __shared__ u16 Bs[3 * 128 * 32];
  const int bid = blockIdx.x;
  const int xcd = bid & 7, idx = bid >> 3;     // 36 per XCD
  const int y = xcd * 2 + (idx & 1);           // M-panel 0..15
  const int r2 = idx >> 1;                     // 0..17
  const int xt = r2 % 6, z = r2 / 6;           // n-tile, matrix id
  const u16* BT = z == 0 ? wqT : (z == 1 ? wkT : wvT);
  const float* bias = z == 0 ? bq : (z == 1 ? bk : bv);
  u16* outp = z == 0 ? qo : (z == 1 ? ko : vo);
  const float scale = z == 0 ? 0.125f : 1.0f;   // DK^-0.5 folded into q
  const int m0 = y * 128, n0 = xt * 128;
  f32x4 acc[2][4];
  #pragma unroll
  for (int a = 0; a < 2; ++a)
    #pragma unroll
    for (int bb = 0; bb < 4; ++bb) acc[a][bb] = (f32x4){0.f, 0.f, 0.f, 0.f};
  gemm_tile_w8(A, BT, D_, D_ / 32, m0, n0, 0, As, Bs, acc);
  const int tid = threadIdx.x;
  const int w = tid >> 6, lane = tid & 63;
  const int lr = lane & 15, hi = lane >> 4;
  const int wm = (w >> 1) * 32, wn = (w & 1) * 64;
  #pragma unroll
  for (int rt = 0; rt < 2; ++rt)
    #pragma unroll
    for (int ct = 0; ct < 4; ++ct)
      #pragma unroll
      for (int r = 0; r < 4; ++r) {
        int m = m0 + wm + rt * 16 + hi * 4 + r;
        int n = n0 + wn + ct * 16 + lr;
        float val = (acc[rt][ct][r] + bias[n]) * scale;
        int b = m >> 9, t = m & 511, hh = n >> 6, d = n & 63;
        if (z < 2) outp[(((size_t)b * H_ + hh) * T_ + t) * DK_ + d] = f2bf(val);
        else       outp[(((size_t)b * H_ + hh) * DK_ + d) * T_ + t] = f2bf(val);
      }
}

// split-K GEMM -> bf16 partials part[kz][M][N]; 1-D grid, XCD-aware (nx n-tiles)
__global__ __launch_bounds__(512) void gemm_part_bf16(
    const u16* __restrict__ A, const u16* __restrict__ BT,
    u16* __restrict__ part, int M, int N, int K, int Ksplit, int nx)
{
  __shared__ u16 As[3 * 128 * 32];
  __shared__ u16 Bs[3 * 128 * 32];
  const int bid = blockIdx.x;
  const int xcd = bid & 7, idx = bid >> 3;
  const int y = xcd * 2 + (idx & 1);           // M-panel 0..15
  const int r2 = idx >> 1;
  const int xt = r2 % nx, kz = r2 / nx;
  const int m0 = y * 128, n0 = xt * 128;
  f32x4 acc[2][4];
  #pragma unroll
  for (int a = 0; a < 2; ++a)
    #pragma unroll
    for (int bb = 0; bb < 4; ++bb) acc[a][bb] = (f32x4){0.f, 0.f, 0.f, 0.f};
  gemm_tile_w8(A, BT, K, Ksplit / 32, m0, n0, kz * Ksplit, As, Bs, acc);
  const int tid = threadIdx.x;
  const int w = tid >> 6, lane = tid & 63;
  const int lr = lane & 15, hi = lane >> 4;
  const int wm = (w >> 1) * 32, wn = (w & 1) * 64;
  u16* pp = part + (size_t)kz * M * N;
  #pragma unroll
  for (int rt = 0; rt < 2; ++rt)
    #pragma unroll
    for (int ct = 0; ct < 4; ++ct)
      #pragma unroll
      for (int r = 0; r < 4; ++r) {
        int m = m0 + wm + rt * 16 + hi * 4 + r;
        int n = n0 + wn + ct * 16 + lr;
        pp[(size_t)m * N + n] = f2bf(acc[rt][ct][r]);
      }
}

// proj reduce (4 bf16 partials) + x + bp, fused LN2 -> x1 (f32) + h2 (bf16)
// 192 threads/row; thread t owns 4 contiguous cols
__global__ __launch_bounds__(192) void reduce_ln(
    const u16* __restrict__ part, const float* __restrict__ x, const float* __restrict__ bp,
    const float* __restrict__ g, const float* __restrict__ bta,
    float* __restrict__ x1, u16* __restrict__ h2)
{
  const int row = blockIdx.x;
  const int tid = threadIdx.x;              // 0..191
  const int c0 = tid * 4;
  const size_t base = (size_t)row * D_ + c0;
  const size_t slab = (size_t)NTOK * D_;
  float4 xv = *(const float4*)&x[base];
  float4 bv = *(const float4*)&bp[c0];
  float v[4] = {xv.x + bv.x, xv.y + bv.y, xv.z + bv.z, xv.w + bv.w};
  #pragma unroll
  for (int kz = 0; kz < 4; ++kz) {
    u16x4 pv = *(const u16x4*)&part[kz * slab + base];
    #pragma unroll
    for (int j = 0; j < 4; ++j) v[j] += bf2f(pv[j]);
  }
  float s = v[0] + v[1] + v[2] + v[3];
  float sq = v[0] * v[0] + v[1] * v[1] + v[2] * v[2] + v[3] * v[3];
  #pragma unroll
  for (int o = 32; o > 0; o >>= 1) { s += __shfl_down(s, o); sq += __shfl_down(sq, o); }
  __shared__ float ss[3], s2[3];
  int w = tid >> 6;
  if ((tid & 63) == 0) { ss[w] = s; s2[w] = sq; }
  __syncthreads();
  s = ss[0] + ss[1] + ss[2];
  sq = s2[0] + s2[1] + s2[2];
  float mean = s * (1.0f / 768.0f);
  float inv = rsqrtf(sq * (1.0f / 768.0f) - mean * mean + 1e-5f);
  float4 gv = *(const float4*)&g[c0];
  float4 tv = *(const float4*)&bta[c0];
  float4 xo = {v[0], v[1], v[2], v[3]};
  *(float4*)&x1[base] = xo;
  u16x4 ho;
  ho[0] = f2bf((v[0] - mean) * inv * gv.x + tv.x);
  ho[1] = f2bf((v[1] - mean) * inv * gv.y + tv.y);
  ho[2] = f2bf((v[2] - mean) * inv * gv.z + tv.z);
  ho[3] = f2bf((v[3] - mean) * inv * gv.w + tv.w);
  *(u16x4*)&h2[base] = ho;
}

// FFN2 stage 2: out = sum of 4 bf16 partials + fc2b + x1 (8 elems/thread)
__global__ __launch_bounds__(256) void reduce_out(
    const u16* __restrict__ part, const float* __restrict__ x1,
    const float* __restrict__ bias, float* __restrict__ out)
{
  const size_t base = ((size_t)blockIdx.x * 256 + threadIdx.x) * 8;
  const size_t slab = (size_t)NTOK * D_;
  const int nb = (int)(base % D_);
  float s[8];
  float4 a0 = *(const float4*)&x1[base];
  float4 a1 = *(const float4*)&x1[base + 4];
  float4 b0 = *(const float4*)&bias[nb];
  float4 b1 = *(const float4*)&bias[nb + 4];
  s[0] = a0.x + b0.x; s[1] = a0.y + b0.y; s[2] = a0.z + b0.z; s[3] = a0.w + b0.w;
  s[4] = a1.x + b1.x; s[5] = a1.y + b1.y; s[6] = a1.z + b1.z; s[7] = a1.w + b1.w;
  #pragma unroll
  for (int kz = 0; kz < 4; ++kz) {
    u16x8 pv = *(const u16x8*)&part[kz * slab + base];
    #pragma unroll
    for (int j = 0; j < 8; ++j) s[j] += bf2f(pv[j]);
  }
  float4 o0 = {s[0], s[1], s[2], s[3]};
  float4 o1 = {s[4], s[5], s[6], s[7]};
  *(float4*)&out[base]     = o0;
  *(float4*)&out[base + 4] = o1;
}

// FFN1: gelu epilogue -> bf16; 1-D grid (384), XCD-aware (24 n-tiles)
__global__ __launch_bounds__(512) void gemm_gelu(
    const u16* __restrict__ A, const u16* __restrict__ BT,
    const float* __restrict__ bias, u16* __restrict__ outp, int M, int N, int K)
{
  __shared__ u16 As[3 * 128 * 32];
  __shared__ u16 Bs[3 * 128 * 32];
  const int bid = blockIdx.x;
  const int xcd = bid & 7, idx = bid >> 3;     // 48 per XCD
  const int y = xcd * 2 + (idx & 1);           // M-panel 0..15
  const int xt = idx >> 1;                     // n-tile 0..23
  const int m0 = y * 128, n0 = xt * 128;
  f32x4 acc[2][4];
  #pragma unroll
  for (int a = 0; a < 2; ++a)
    #pragma unroll
    for (int bb = 0; bb < 4; ++bb) acc[a][bb] = (f32x4){0.f, 0.f, 0.f, 0.f};
  gemm_tile_w8(A, BT, K, K / 32, m0, n0, 0, As, Bs, acc);
  const int tid = threadIdx.x;
  const int w = tid >> 6, lane = tid & 63;
  const int lr = lane & 15, hi = lane >> 4;
  const int wm = (w >> 1) * 32, wn = (w & 1) * 64;
  #pragma unroll
  for (int rt = 0; rt < 2; ++rt)
    #pragma unroll
    for (int ct = 0; ct < 4; ++ct)
      #pragma unroll
      for (int r = 0; r < 4; ++r) {
        int m = m0 + wm + rt * 16 + hi * 4 + r;
        int n = n0 + wn + ct * 16 + lr;
        float val = acc[rt][ct][r] + bias[n];
        outp[(size_t)m * N + n] = f2bf(gelu_f(val));
      }
}

// ---------------- attention v4: 32 q-rows per block, causal column skipping,
// scores in registers, P bf16 swizzled LDS, V-frags shared across row-groups.
__global__ __launch_bounds__(256) void attn_kernel(
    const u16* __restrict__ q, const u16* __restrict__ k, const u16* __restrict__ vT,
    const u16* __restrict__ biasM, u16* __restrict__ ao)
{
  __shared__ u16 P[32 * 512];            // unnormalized bf16 P, XOR-swizzled (32 KB)
  __shared__ float pmax[128], psum[128]; // [wave][row 0..31]
  const int tid = threadIdx.x;
  const int w = tid >> 6, lane = tid & 63;
  const int lr = lane & 15, hi = lane >> 4, lk = hi * 8;

  const int bid = blockIdx.x;
  const int xcd = bid & 7, idx = bid >> 3;     // 96 blocks per XCD
  const int bh = xcd * 6 + (idx >> 4);         // 6 bh per XCD
  const int i0 = (idx & 15) * 32;
  const int b = bh / H_, h = bh % H_;
  const int tmax = (i0 == 0) ? 31 : ((i0 >> 4) + 1);   // 16-col tiles
  const int nks  = (i0 == 0) ? 16 : ((i0 >> 5) + 1);   // 32-col PV k-tiles

  bfx8 qf[2][2];
  #pragma unroll
  for (int g = 0; g < 2; ++g)
    #pragma unroll
    for (int ks = 0; ks < 2; ++ks)
      qf[g][ks] = *(const bfx8*)(q + ((size_t)bh * T_ + i0 + g * 16 + lr) * DK_ + ks * 32 + lk);
  f32x4 acc[8][2];
  float mx[2][4];
  #pragma unroll
  for (int g = 0; g < 2; ++g)
    #pragma unroll
    for (int r = 0; r < 4; ++r) mx[g][r] = -3.4e38f;
  #pragma unroll
  for (int ct = 0; ct < 8; ++ct) {
    const int t = ct * 4 + w;
    if (t > tmax) continue;              // wave-uniform skip
    const int j0 = t * 16;
    bfx8 kf0 = *(const bfx8*)(k + ((size_t)bh * T_ + j0 + lr) * DK_ + lk);
    bfx8 kf1 = *(const bfx8*)(k + ((size_t)bh * T_ + j0 + lr) * DK_ + 32 + lk);
    const int j = j0 + lr;
    __builtin_amdgcn_s_setprio(1);
    #pragma unroll
    for (int g = 0; g < 2; ++g) {
      f32x4 a0 = (f32x4){0.f, 0.f, 0.f, 0.f};
      a0 = __builtin_amdgcn_mfma_f32_16x16x32_bf16(qf[g][0], kf0, a0, 0, 0, 0);
      a0 = __builtin_amdgcn_mfma_f32_16x16x32_bf16(qf[g][1], kf1, a0, 0, 0, 0);
      acc[ct][g] = a0;
    }
    __builtin_amdgcn_s_setprio(0);
    #pragma unroll
    for (int g = 0; g < 2; ++g)
      #pragma unroll
      for (int r = 0; r < 4; ++r) {
        int i = i0 + g * 16 + hi * 4 + r;
        float s = acc[ct][g][r] + bf2f(biasM[((size_t)b * T_ + i) * T_ + j]);
        if (j > i && i != 0) s = NEGV;   // causal; CLS row 0 fully visible
        acc[ct][g][r] = s;
        mx[g][r] = fmaxf(mx[g][r], s);
      }
  }
  #pragma unroll
  for (int o = 1; o < 16; o <<= 1)
    #pragma unroll
    for (int g = 0; g < 2; ++g)
      #pragma unroll
      for (int r = 0; r < 4; ++r) mx[g][r] = fmaxf(mx[g][r], __shfl_xor(mx[g][r], o));
  if (lr == 0) {
    #pragma unroll
    for (int g = 0; g < 2; ++g)
      #pragma unroll
      for (int r = 0; r < 4; ++r) pmax[w * 32 + g * 16 + hi * 4 + r] = mx[g][r];
  }
  __syncthreads();

  float M2[2][4], sm[2][4];
  #pragma unroll
  for (int g = 0; g < 2; ++g)
    #pragma unroll
    for (int r = 0; r < 4; ++r) {
      int row = g * 16 + hi * 4 + r;
      M2[g][r] = fmaxf(fmaxf(pmax[row], pmax[32 + row]), fmaxf(pmax[64 + row], pmax[96 + row]));
      sm[g][r] = 0.f;
    }
  char* Pb = (char*)P;
  #pragma unroll
  for (int ct = 0; ct < 8; ++ct) {
    const int t = ct * 4 + w;
    if (t > tmax) continue;
    const int col = t * 16 + lr;
    #pragma unroll
    for (int g = 0; g < 2; ++g)
      #pragma unroll
      for (int r = 0; r < 4; ++r) {
        float pexp = __expf(acc[ct][g][r] - M2[g][r]);
        sm[g][r] += pexp;
        int row = g * 16 + hi * 4 + r;
        int byte = (row * 1024 + col * 2) ^ ((row & 7) << 4);
        *(u16*)(Pb + byte) = f2bf(pexp);
      }
  }
  #pragma unroll
  for (int o = 1; o < 16; o <<= 1)
    #pragma unroll
    for (int g = 0; g < 2; ++g)
      #pragma unroll
      for (int r = 0; r < 4; ++r) sm[g][r] += __shfl_xor(sm[g][r], o);
  if (lr == 0) {
    #pragma unroll
    for (int g = 0; g < 2; ++g)
      #pragma unroll
      for (int r = 0; r < 4; ++r) psum[w * 32 + g * 16 + hi * 4 + r] = sm[g][r];
  }
  __syncthreads();

  float rinv[2][4];
  #pragma unroll
  for (int g = 0; g < 2; ++g)
    #pragma unroll
    for (int r = 0; r < 4; ++r) {
      int row = g * 16 + hi * 4 + r;
      rinv[g][r] = 1.0f / (psum[row] + psum[32 + row] + psum[64 + row] + psum[96 + row]);
    }

  {
    const int n0 = w * 16;
    f32x4 oa0 = (f32x4){0.f, 0.f, 0.f, 0.f};
    f32x4 oa1 = (f32x4){0.f, 0.f, 0.f, 0.f};
    for (int ks = 0; ks < nks; ++ks) {
      bfx8 vf = *(const bfx8*)(vT + ((size_t)bh * DK_ + n0 + lr) * T_ + ks * 32 + lk);
      int byte0 = (lr * 1024 + (ks * 32 + lk) * 2) ^ ((lr & 7) << 4);
      int byte1 = ((16 + lr) * 1024 + (ks * 32 + lk) * 2) ^ ((lr & 7) << 4);
      bfx8 pa0 = *(const bfx8*)(Pb + byte0);
      bfx8 pa1 = *(const bfx8*)(Pb + byte1);
      __builtin_amdgcn_s_setprio(1);
      oa0 = __builtin_amdgcn_mfma_f32_16x16x32_bf16(pa0, vf, oa0, 0, 0, 0);
      oa1 = __builtin_amdgcn_mfma_f32_16x16x32_bf16(pa1, vf, oa1, 0, 0, 0);
      __builtin_amdgcn_s_setprio(0);
    }
    #pragma unroll
    for (int r = 0; r < 4; ++r) {
      int i = i0 + hi * 4 + r;
      ao[((size_t)b * T_ + i) * D_ + h * DK_ + n0 + lr] = f2bf(oa0[r] * rinv[0][r]);
    }
    #pragma unroll
    for (int r = 0; r < 4; ++r) {
      int i = i0 + 16 + hi * 4 + r;
      ao[((size_t)b * T_ + i) * D_ + h * DK_ + n0 + lr] = f2bf(oa1[r] * rinv[1][r]);
    }
  }
}

extern "C" void kernel_launch(void* const* d_in, const int* in_sizes, int n_in,
                              void* d_out, int out_size, void* d_ws, size_t ws_size,
                              hipStream_t stream) {
  (void)in_sizes; (void)n_in; (void)out_size; (void)ws_size;
  const float* x    = (const float*)d_in[0];
  const float* tmat = (const float*)d_in[1];
  const int*   pad  = (const int*)d_in[2];
  const float* wq = (const float*)d_in[3];  const float* bq = (const float*)d_in[4];
  const float* wk = (const float*)d_in[5];  const float* bk = (const float*)d_in[6];
  const float* wv = (const float*)d_in[7];  const float* bv = (const float*)d_in[8];
  const float* wp = (const float*)d_in[9];  const float* bp = (const float*)d_in[10];
  const float* tb1w = (const float*)d_in[11]; const float* tb1b = (const float*)d_in[12];
  const float* tb2w = (const float*)d_in[13]; const float* tb2b = (const float*)d_in[14];
  const float* fc1w = (const float*)d_in[15]; const float* fc1b = (const float*)d_in[16];
  const float* fc2w = (const float*)d_in[17]; const float* fc2b = (const float*)d_in[18];
  const float* ln1g = (const float*)d_in[19]; const float* ln1b = (const float*)d_in[20];
  const float* ln2g = (const float*)d_in[21]; const float* ln2b = (const float*)d_in[22];
  float* out = (float*)d_out;

  // ---- workspace layout
  char* p = (char*)d_ws;
  u16* wqT  = (u16*)p; p += (size_t)768 * 768 * 2;
  u16* wkT  = (u16*)p; p += (size_t)768 * 768 * 2;
  u16* wvT  = (u16*)p; p += (size_t)768 * 768 * 2;
  u16* wpT  = (u16*)p; p += (size_t)768 * 768 * 2;
  u16* fc1T = (u16*)p; p += (size_t)768 * 3072 * 2;
  u16* fc2T = (u16*)p; p += (size_t)3072 * 768 * 2;
  float* x1 = (float*)p; p += (size_t)NTOK * D_ * 4;
  u16* gbuf = (u16*)p; p += (size_t)NTOK * FF_ * 2;
  u16* hbuf = (u16*)p; p += (size_t)NTOK * D_ * 2;
  u16* qb   = (u16*)p; p += (size_t)NTOK * D_ * 2;
  u16* kb   = (u16*)p; p += (size_t)NTOK * D_ * 2;
  u16* vTb  = (u16*)p; p += (size_t)NTOK * D_ * 2;
  u16* biasM = (u16*)p; p += (size_t)B_ * T_ * T_ * 2;
  u16* ao   = (u16*)p; p += (size_t)NTOK * D_ * 2;
  u16* h2   = (u16*)p; p += (size_t)NTOK * D_ * 2;
  u16* partF = (u16*)p; p += (size_t)4 * NTOK * D_ * 2;   // bf16 partials (4 slabs)

  // prep: transposes + LN1 + bias MLP in one dispatch
  prep_kernel<<<13056, 256, 0, stream>>>(x, wq, wk, wv, wp, fc1w, fc2w,
                                         wqT, wkT, wvT, wpT, fc1T, fc2T,
                                         ln1g, ln1b, hbuf,
                                         tmat, pad, tb1w, tb1b, tb2w, tb2b, biasM);

  gemm_qkv<<<288, 512, 0, stream>>>(hbuf, wqT, wkT, wvT, bq, bk, bv, qb, kb, vTb);
  attn_kernel<<<768, 256, 0, stream>>>(qb, kb, vTb, biasM, ao);

  // proj: split-K=4 bf16 partials (384 blocks), then reduce fused with LN2
  gemm_part_bf16<<<384, 512, 0, stream>>>(ao, wpT, partF, NTOK, 768, 768, 192, 6);
  reduce_ln<<<NTOK, 192, 0, stream>>>(partF, x, bp, ln2g, ln2b, x1, h2);

  // FFN1 (384 blocks)
  gemm_gelu<<<384, 512, 0, stream>>>(h2, fc1T, fc1b, gbuf, NTOK, FF_, 768);

  // FFN2: split-K=4 (384 blocks) -> bf16 partials, then vectorized reduce
  gemm_part_bf16<<<384, 512, 0, stream>>>(gbuf, fc2T, partF, NTOK, 768, 3072, 768, 6);
  reduce_out<<<NTOK * D_ / 8 / 256, 256, 0, stream>>>(partF, x1, fc2b, out);
}